// Round 1
// baseline (988.193 us; speedup 1.0000x reference)
//
#include <hip/hip_runtime.h>
#include <hip/hip_bf16.h>
#include <stdint.h>

// Problem constants
#define NB   2
#define NH   64
#define NHK  8
#define SQ   1024
#define SK   1024
#define DH   128
#define HID  8192     // NH*DH
#define MROWS 2048    // NB*SQ

typedef unsigned short u16;
typedef __bf16 bf16_t;
typedef bf16_t bf16x8 __attribute__((ext_vector_type(8)));
typedef float  f32x4  __attribute__((ext_vector_type(4)));
typedef u16    u16x8  __attribute__((ext_vector_type(8)));
typedef u16    u16x4  __attribute__((ext_vector_type(4)));

#define DEV __device__ __forceinline__

DEV u16 f2bf(float f) {
  uint32_t u = __builtin_bit_cast(uint32_t, f);
  u += 0x7fffu + ((u >> 16) & 1u);   // RNE
  return (u16)(u >> 16);
}

DEV bf16x8 pack8(const float* v) {
  u16x8 r;
#pragma unroll
  for (int i = 0; i < 8; ++i) r[i] = f2bf(v[i]);
  return __builtin_bit_cast(bf16x8, r);
}

DEV f32x4 mfma16(bf16x8 a, bf16x8 b, f32x4 c) {
  return __builtin_amdgcn_mfma_f32_16x16x32_bf16(a, b, c, 0, 0, 0);
}

// async global->LDS, 16B per lane; lds dest must be wave-uniform base
DEV void gload_lds16(const void* g, void* l) {
  __builtin_amdgcn_global_load_lds(
      (const __attribute__((address_space(1))) void*)g,
      (__attribute__((address_space(3))) void*)l, 16, 0, 0);
}

// ---------------------------------------------------------------------------
// Kernel 1: wo [K=8192][N=8192] fp32 -> Wt [N][K] bf16 (transpose + convert)
// ---------------------------------------------------------------------------
__global__ __launch_bounds__(256) void k_wo_t(const float* __restrict__ wo,
                                              u16* __restrict__ wt) {
  __shared__ u16 tile[64][72];  // [k-local][n-local], padded
  const int t  = threadIdx.x;
  const int k0 = (blockIdx.x & 127) * 64;
  const int n0 = (blockIdx.x >> 7) * 64;
  const int r  = t >> 4, cg = t & 15;
#pragma unroll
  for (int p = 0; p < 4; ++p) {
    int row = r + p * 16;  // k-local
    float4 v = *(const float4*)(wo + (size_t)(k0 + row) * 8192 + n0 + cg * 4);
    tile[row][cg * 4 + 0] = f2bf(v.x);
    tile[row][cg * 4 + 1] = f2bf(v.y);
    tile[row][cg * 4 + 2] = f2bf(v.z);
    tile[row][cg * 4 + 3] = f2bf(v.w);
  }
  __syncthreads();
#pragma unroll
  for (int p = 0; p < 4; ++p) {
    int row = r + p * 16;  // n-local
    u16x4 ov;
    ov[0] = tile[cg * 4 + 0][row];
    ov[1] = tile[cg * 4 + 1][row];
    ov[2] = tile[cg * 4 + 2][row];
    ov[3] = tile[cg * 4 + 3][row];
    *(u16x4*)(wt + (size_t)(n0 + row) * 8192 + k0 + cg * 4) = ov;
  }
}

// ---------------------------------------------------------------------------
// Kernel 2: keys fp32 [head][kpos][d] -> Kws bf16, row kpos=256B,
//           16B-chunk XOR-swizzled by (kpos&7)<<4  (bank-conflict-free LDS)
// ---------------------------------------------------------------------------
__global__ __launch_bounds__(256) void k_cvt_k(const float* __restrict__ keys,
                                               char* __restrict__ kws) {
  int c = blockIdx.x * 256 + threadIdx.x;  // 262144 chunks of 8 elems
  int head = c >> 14;
  int kpos = (c >> 4) & 1023;
  int dg   = c & 15;
  const float* src = keys + ((size_t)head * 1024 + kpos) * 128 + dg * 8;
  float t[8];
  *(float4*)t       = *(const float4*)src;
  *(float4*)(t + 4) = *(const float4*)(src + 4);
  u16x8 r;
#pragma unroll
  for (int i = 0; i < 8; ++i) r[i] = f2bf(t[i]);
  *(u16x8*)(kws + (size_t)head * 262144 + kpos * 256 +
            ((dg * 16) ^ ((kpos & 7) << 4))) = r;
}

// ---------------------------------------------------------------------------
// Kernel 3: values fp32 [head][kpos][d] -> Vws bf16 TRANSPOSED [head][d][kpos],
//           row d=2048B, 16B-chunk XOR-swizzled by (d&7)<<4
// ---------------------------------------------------------------------------
__global__ __launch_bounds__(256) void k_cvt_v(const float* __restrict__ values,
                                               char* __restrict__ vws) {
  int c = blockIdx.x * 256 + threadIdx.x;  // 262144 chunks of 8 kpos
  int head = c >> 14;
  int kg   = (c >> 7) & 127;
  int d    = c & 127;
  const float* src = values + (size_t)head * 131072 + (size_t)kg * 8 * 128 + d;
  u16x8 r;
#pragma unroll
  for (int j = 0; j < 8; ++j) r[j] = f2bf(src[j * 128]);
  *(u16x8*)(vws + (size_t)head * 262144 + d * 2048 +
            ((kg * 16) ^ ((d & 7) << 4))) = r;
}

// ---------------------------------------------------------------------------
// Kernel 4: flash attention. Block=256 thr (4 waves), QBLK=128 (32 rows/wave),
// KVBLK=64. S = Q·K^T via mfma(qf, kf): C row=q((l>>4)*4+r), col=kpos(l&15).
// ---------------------------------------------------------------------------
__global__ __launch_bounds__(256) void k_attn(
    const float* __restrict__ xq, const char* __restrict__ kws,
    const char* __restrict__ vws, const float* __restrict__ mask,
    u16* __restrict__ abf) {
  __shared__ char kt[16384];        // [kpos 64][d 128] bf16, swizzled rows
  __shared__ char vt[16384];        // [d 128][kl 64] bf16, swizzled rows
  __shared__ u16 pl[4 * 32 * 88];   // per-wave P [32][88-padded]

  const int b = blockIdx.z, h = blockIdx.y;
  const int q0 = blockIdx.x * 128;
  const int hk = h >> 3;
  const int tid = threadIdx.x;
  const int w = tid >> 6, l = tid & 63;
  const int lr = l & 15, lg = l >> 4;

  // Q fragments in registers (A-operand: row=l&15, k=(l>>4)*8+j within 32-chunk)
  bf16x8 qf[2][4];
  {
    const float* qb = xq + (((size_t)(b * NH + h) * SQ) + q0 + w * 32) * DH;
#pragma unroll
    for (int mi = 0; mi < 2; ++mi)
#pragma unroll
      for (int c = 0; c < 4; ++c) {
        const float* qp = qb + (size_t)(mi * 16 + lr) * DH + c * 32 + lg * 8;
        float t[8];
        *(float4*)t       = *(const float4*)qp;
        *(float4*)(t + 4) = *(const float4*)(qp + 4);
        qf[mi][c] = pack8(t);
      }
  }

  f32x4 o[2][8];
#pragma unroll
  for (int mi = 0; mi < 2; ++mi)
#pragma unroll
    for (int nd = 0; nd < 8; ++nd) o[mi][nd] = (f32x4){0.f, 0.f, 0.f, 0.f};
  float mrun[2][4], lrun[2][4];
#pragma unroll
  for (int mi = 0; mi < 2; ++mi)
#pragma unroll
    for (int r = 0; r < 4; ++r) { mrun[mi][r] = -1e30f; lrun[mi][r] = 0.f; }

  const char*  kb_base = kws + (size_t)(b * NHK + hk) * ((size_t)SK * 256);
  const char*  vb_base = vws + (size_t)(b * NHK + hk) * ((size_t)DH * 2048);
  const float* mk_base = mask + (size_t)b * SQ * SK;
  const float SCALE = 0.08838834764831845f;  // 1/sqrt(128)
  const float L2E   = 1.4426950408889634f;
  u16* plw = pl + w * 32 * 88;

  for (int kb = 0; kb < SK; kb += 64) {
    // ---- stage K tile (16KB) and V tile (16KB), pre-swizzled in ws ----
#pragma unroll
    for (int j = 0; j < 4; ++j) {
      int is = w * 4 + j;  // wave-uniform issue id 0..15
      gload_lds16(kb_base + (size_t)kb * 256 + is * 1024 + l * 16, kt + is * 1024);
      int c2 = is * 64 + l;
      int d = c2 >> 3, part = c2 & 7;
      gload_lds16(vb_base + (size_t)d * 2048 + kb * 2 + part * 16, vt + is * 1024);
    }
    __syncthreads();

    // ---- QK^T: S[32q x 64k] per wave ----
    f32x4 s[2][4];
#pragma unroll
    for (int mi = 0; mi < 2; ++mi)
#pragma unroll
      for (int ni = 0; ni < 4; ++ni) s[mi][ni] = (f32x4){0.f, 0.f, 0.f, 0.f};
#pragma unroll
    for (int ni = 0; ni < 4; ++ni)
#pragma unroll
      for (int c = 0; c < 4; ++c) {
        int row = ni * 16 + lr;  // kpos-local
        int byt = row * 256 + (((c * 32 + lg * 8) * 2) ^ ((row & 7) << 4));
        bf16x8 kf = *(const bf16x8*)(kt + byt);
        s[0][ni] = mfma16(qf[0][c], kf, s[0][ni]);
        s[1][ni] = mfma16(qf[1][c], kf, s[1][ni]);
      }

    // ---- mask + online softmax (row = lg*4+r within 16; reduce over l&15) ----
#pragma unroll
    for (int mi = 0; mi < 2; ++mi) {
      float x[4][4];
#pragma unroll
      for (int ni = 0; ni < 4; ++ni)
#pragma unroll
        for (int r = 0; r < 4; ++r) {
          int grow = q0 + w * 32 + mi * 16 + lg * 4 + r;
          float mv = mk_base[(size_t)grow * SK + kb + ni * 16 + lr];
          x[ni][r] = s[mi][ni][r] * SCALE + mv;
        }
      float tm[4], fac[4];
#pragma unroll
      for (int r = 0; r < 4; ++r) {
        float v = fmaxf(fmaxf(x[0][r], x[1][r]), fmaxf(x[2][r], x[3][r]));
        v = fmaxf(v, __shfl_xor(v, 1));
        v = fmaxf(v, __shfl_xor(v, 2));
        v = fmaxf(v, __shfl_xor(v, 4));
        v = fmaxf(v, __shfl_xor(v, 8));
        float mnew = fmaxf(mrun[mi][r], v);
        fac[r] = exp2f((mrun[mi][r] - mnew) * L2E);
        mrun[mi][r] = mnew;
        tm[r] = mnew;
      }
#pragma unroll
      for (int ni = 0; ni < 4; ++ni)
#pragma unroll
        for (int r = 0; r < 4; ++r) {
          float p = exp2f((x[ni][r] - tm[r]) * L2E);
          x[ni][r] = p;
          plw[(mi * 16 + lg * 4 + r) * 88 + ni * 16 + lr] = f2bf(p);
        }
#pragma unroll
      for (int r = 0; r < 4; ++r) {
        float sum = x[0][r] + x[1][r] + x[2][r] + x[3][r];
        sum += __shfl_xor(sum, 1);
        sum += __shfl_xor(sum, 2);
        sum += __shfl_xor(sum, 4);
        sum += __shfl_xor(sum, 8);
        lrun[mi][r] = lrun[mi][r] * fac[r] + sum;
      }
#pragma unroll
      for (int nd = 0; nd < 8; ++nd)
#pragma unroll
        for (int r = 0; r < 4; ++r) o[mi][nd][r] *= fac[r];
    }

    // ---- PV: O += P[32x64] * V[64x128] ----
#pragma unroll
    for (int ks = 0; ks < 2; ++ks) {
      bf16x8 pf0 = *(const bf16x8*)((const char*)plw + (0 * 16 + lr) * 176 + ks * 64 + lg * 16);
      bf16x8 pf1 = *(const bf16x8*)((const char*)plw + (1 * 16 + lr) * 176 + ks * 64 + lg * 16);
#pragma unroll
      for (int nd = 0; nd < 8; ++nd) {
        int d = nd * 16 + lr;
        int byt = d * 128 + (((ks * 32 + lg * 8) * 2) ^ ((d & 7) << 4));
        bf16x8 vf = *(const bf16x8*)(vt + byt);
        o[0][nd] = mfma16(pf0, vf, o[0][nd]);
        o[1][nd] = mfma16(pf1, vf, o[1][nd]);
      }
    }
    __syncthreads();
  }

  // ---- epilogue: normalize, write bf16 A row [b*1024+q][h*128+d] ----
#pragma unroll
  for (int mi = 0; mi < 2; ++mi)
#pragma unroll
    for (int nd = 0; nd < 8; ++nd)
#pragma unroll
      for (int r = 0; r < 4; ++r) {
        int grow = q0 + w * 32 + mi * 16 + lg * 4 + r;
        size_t m = (size_t)b * SQ + grow;
        int col = h * DH + nd * 16 + lr;
        abf[m * HID + col] = f2bf(o[mi][nd][r] / lrun[mi][r]);
      }
}

// ---------------------------------------------------------------------------
// Kernel 5: C[2048][8192] fp32 = A[2048][8192] bf16 · Wt[8192][8192]^T bf16
// m97-style: 128x128 tile, BK=32, 4 waves (2x2), 4x4 acc frags, gload_lds16.
// ---------------------------------------------------------------------------
__global__ __launch_bounds__(256) void k_gemm(const u16* __restrict__ A,
                                              const u16* __restrict__ Bt,
                                              float* __restrict__ C) {
  __shared__ char As[8192];
  __shared__ char Bs[8192];
  const int bid = blockIdx.x;
  const int m0 = (bid & 15) * 128;   // M fast: blocks sharing Bt-strip adjacent
  const int n0 = (bid >> 4) * 128;
  const int tid = threadIdx.x;
  const int w = tid >> 6, l = tid & 63;
  const int lr = l & 15, lg = l >> 4;
  const int wr = w >> 1, wc = w & 1;

  f32x4 acc[4][4];
#pragma unroll
  for (int mi = 0; mi < 4; ++mi)
#pragma unroll
    for (int ni = 0; ni < 4; ++ni) acc[mi][ni] = (f32x4){0.f, 0.f, 0.f, 0.f};

  const char* Ab = (const char*)A;
  const char* Bb = (const char*)Bt;

  for (int kt = 0; kt < 8192; kt += 32) {
#pragma unroll
    for (int j = 0; j < 2; ++j) {
      int is = j * 4 + w;            // wave-uniform 0..7
      int chunk = is * 64 + l;       // 0..511
      int row = chunk >> 2, cg = chunk & 3;
      gload_lds16(Ab + ((size_t)(m0 + row) * 8192 + kt + cg * 8) * 2, As + is * 1024);
      gload_lds16(Bb + ((size_t)(n0 + row) * 8192 + kt + cg * 8) * 2, Bs + is * 1024);
    }
    __syncthreads();
    bf16x8 af[4], bfr[4];
#pragma unroll
    for (int i = 0; i < 4; ++i) {
      af[i]  = *(const bf16x8*)(As + (wr * 64 + i * 16 + lr) * 64 + lg * 16);
      bfr[i] = *(const bf16x8*)(Bs + (wc * 64 + i * 16 + lr) * 64 + lg * 16);
    }
#pragma unroll
    for (int mi = 0; mi < 4; ++mi)
#pragma unroll
      for (int ni = 0; ni < 4; ++ni)
        acc[mi][ni] = mfma16(af[mi], bfr[ni], acc[mi][ni]);
    __syncthreads();
  }

#pragma unroll
  for (int mi = 0; mi < 4; ++mi)
#pragma unroll
    for (int ni = 0; ni < 4; ++ni)
#pragma unroll
      for (int r = 0; r < 4; ++r)
        C[(size_t)(m0 + wr * 64 + mi * 16 + lg * 4 + r) * 8192 +
          n0 + wc * 64 + ni * 16 + lr] = acc[mi][ni][r];
}

// ---------------------------------------------------------------------------
extern "C" void kernel_launch(void* const* d_in, const int* in_sizes, int n_in,
                              void* d_out, int out_size, void* d_ws, size_t ws_size,
                              hipStream_t stream) {
  const float* xq     = (const float*)d_in[0];
  const float* keys   = (const float*)d_in[1];
  const float* values = (const float*)d_in[2];
  const float* mask   = (const float*)d_in[3];
  const float* wo     = (const float*)d_in[4];
  float* out = (float*)d_out;

  // ws layout (needs ~176 MB):
  //   [0, 32M)          A bf16 (attn out, [2048][8192])
  //   [32M, 160M)       Wt bf16 (wo^T, [8192][8192])
  //   [+4M][+4M]        Kws / Vws bf16 swizzled
  char* ws = (char*)d_ws;
  u16*  Abf = (u16*)ws;
  u16*  Wt  = (u16*)(ws + 33554432ull);
  char* Kws = ws + 33554432ull + 134217728ull;
  char* Vws = Kws + 4194304ull;

  hipLaunchKernelGGL(k_wo_t,  dim3(16384), dim3(256), 0, stream, wo, Wt);
  hipLaunchKernelGGL(k_cvt_k, dim3(1024),  dim3(256), 0, stream, keys, Kws);
  hipLaunchKernelGGL(k_cvt_v, dim3(1024),  dim3(256), 0, stream, values, Vws);
  hipLaunchKernelGGL(k_attn,  dim3(8, 64, 2), dim3(256), 0, stream,
                     xq, Kws, Vws, mask, Abf);
  hipLaunchKernelGGL(k_gemm,  dim3(1024),  dim3(256), 0, stream, Abf, Wt, out);
}

// Round 2
// 847.114 us; speedup vs baseline: 1.1665x; 1.1665x over previous
//
#include <hip/hip_runtime.h>
#include <hip/hip_bf16.h>
#include <stdint.h>

// Problem constants
#define NB   2
#define NH   64
#define NHK  8
#define SQ   1024
#define SK   1024
#define DH   128
#define HID  8192     // NH*DH
#define MROWS 2048    // NB*SQ

typedef unsigned short u16;
typedef __bf16 bf16_t;
typedef bf16_t bf16x8 __attribute__((ext_vector_type(8)));
typedef float  f32x4  __attribute__((ext_vector_type(4)));
typedef u16    u16x8  __attribute__((ext_vector_type(8)));
typedef u16    u16x4  __attribute__((ext_vector_type(4)));

#define DEV __device__ __forceinline__

DEV u16 f2bf(float f) {
  uint32_t u = __builtin_bit_cast(uint32_t, f);
  u += 0x7fffu + ((u >> 16) & 1u);   // RNE
  return (u16)(u >> 16);
}

DEV bf16x8 pack8(const float* v) {
  u16x8 r;
#pragma unroll
  for (int i = 0; i < 8; ++i) r[i] = f2bf(v[i]);
  return __builtin_bit_cast(bf16x8, r);
}

DEV f32x4 mfma16(bf16x8 a, bf16x8 b, f32x4 c) {
  return __builtin_amdgcn_mfma_f32_16x16x32_bf16(a, b, c, 0, 0, 0);
}

// async global->LDS, 16B per lane; lds dest must be wave-uniform base
DEV void gload_lds16(const void* g, void* l) {
  __builtin_amdgcn_global_load_lds(
      (const __attribute__((address_space(1))) void*)g,
      (__attribute__((address_space(3))) void*)l, 16, 0, 0);
}

// ---------------------------------------------------------------------------
// Kernel 1: wo [K=8192][N=8192] fp32 -> Wt [N][K] bf16 (transpose + convert)
// ---------------------------------------------------------------------------
__global__ __launch_bounds__(256) void k_wo_t(const float* __restrict__ wo,
                                              u16* __restrict__ wt) {
  __shared__ u16 tile[64][72];  // [k-local][n-local], padded
  const int t  = threadIdx.x;
  const int k0 = (blockIdx.x & 127) * 64;
  const int n0 = (blockIdx.x >> 7) * 64;
  const int r  = t >> 4, cg = t & 15;
#pragma unroll
  for (int p = 0; p < 4; ++p) {
    int row = r + p * 16;  // k-local
    float4 v = *(const float4*)(wo + (size_t)(k0 + row) * 8192 + n0 + cg * 4);
    tile[row][cg * 4 + 0] = f2bf(v.x);
    tile[row][cg * 4 + 1] = f2bf(v.y);
    tile[row][cg * 4 + 2] = f2bf(v.z);
    tile[row][cg * 4 + 3] = f2bf(v.w);
  }
  __syncthreads();
#pragma unroll
  for (int p = 0; p < 4; ++p) {
    int row = r + p * 16;  // n-local
    u16x4 ov;
    ov[0] = tile[cg * 4 + 0][row];
    ov[1] = tile[cg * 4 + 1][row];
    ov[2] = tile[cg * 4 + 2][row];
    ov[3] = tile[cg * 4 + 3][row];
    *(u16x4*)(wt + (size_t)(n0 + row) * 8192 + k0 + cg * 4) = ov;
  }
}

// ---------------------------------------------------------------------------
// Kernel 2: keys fp32 [head][kpos][d] -> Kf bf16 FRAGMENT-MAJOR:
//   per head, per 64-row tile t, per (ni,c): 1KB block where lane l holds
//   bf16x8 = K[t*64 + ni*16 + (l&15)][c*32 + (l>>4)*8 + j], j=0..7.
//   k_attn then loads B-fragments as coalesced 1KB wave loads, no LDS.
// ---------------------------------------------------------------------------
__global__ __launch_bounds__(256) void k_cvt_k(const float* __restrict__ keys,
                                               char* __restrict__ kf) {
  int g = blockIdx.x * 256 + threadIdx.x;  // 262144 chunks of 16B
  int l    = g & 63;
  int blk  = (g >> 6) & 15;
  int t    = (g >> 10) & 15;
  int head = g >> 14;
  int ni = blk >> 2, c = blk & 3;
  int row = t * 64 + ni * 16 + (l & 15);
  int col = c * 32 + (l >> 4) * 8;
  const float* src = keys + ((size_t)head * 1024 + row) * 128 + col;
  float tb[8];
  *(float4*)tb       = *(const float4*)src;
  *(float4*)(tb + 4) = *(const float4*)(src + 4);
  u16x8 r;
#pragma unroll
  for (int i = 0; i < 8; ++i) r[i] = f2bf(tb[i]);
  *(u16x8*)(kf + (size_t)g * 16) = r;
}

// ---------------------------------------------------------------------------
// Kernel 3: values fp32 [head][kpos][d] -> Vf bf16 FRAGMENT-MAJOR:
//   per head, per tile t, per (ks,nd): 1KB block where lane l holds
//   bf16x8 = V[t*64 + ks*32 + (l>>4)*8 + j][nd*16 + (l&15)], j=0..7.
// ---------------------------------------------------------------------------
__global__ __launch_bounds__(256) void k_cvt_v(const float* __restrict__ values,
                                               char* __restrict__ vf) {
  int g = blockIdx.x * 256 + threadIdx.x;
  int l    = g & 63;
  int blk  = (g >> 6) & 15;
  int t    = (g >> 10) & 15;
  int head = g >> 14;
  int ks = blk >> 3, nd = blk & 7;
  int k0 = t * 64 + ks * 32 + (l >> 4) * 8;
  int d  = nd * 16 + (l & 15);
  const float* src = values + (size_t)head * 131072 + (size_t)k0 * 128 + d;
  u16x8 r;
#pragma unroll
  for (int j = 0; j < 8; ++j) r[j] = f2bf(src[j * 128]);
  *(u16x8*)(vf + (size_t)g * 16) = r;
}

// ---------------------------------------------------------------------------
// Kernel 4: flash attention, ZERO-barrier main loop. Block=256 (4 waves),
// QBLK=128 (32 q-rows/wave), KVBLK=64. K/V fragments loaded straight from
// the fragment-major global layouts (L2-resident, 1KB coalesced per load).
// Only LDS: per-wave P buffer (padded rows).
// ---------------------------------------------------------------------------
__global__ __launch_bounds__(256) void k_attn(
    const float* __restrict__ xq, const char* __restrict__ kf_g,
    const char* __restrict__ vf_g, const float* __restrict__ mask,
    u16* __restrict__ abf) {
  __shared__ u16 pl[4 * 32 * 88];   // per-wave P [32][88-padded]

  const int b = blockIdx.z, h = blockIdx.y;
  const int q0 = blockIdx.x * 128;
  const int hk = h >> 3;
  const int tid = threadIdx.x;
  const int w = tid >> 6, l = tid & 63;
  const int lr = l & 15, lg = l >> 4;

  // Q fragments in registers (A-operand: row=l&15, k=(l>>4)*8+j per 32-chunk)
  bf16x8 qf[2][4];
  {
    const float* qb = xq + (((size_t)(b * NH + h) * SQ) + q0 + w * 32) * DH;
#pragma unroll
    for (int mi = 0; mi < 2; ++mi)
#pragma unroll
      for (int c = 0; c < 4; ++c) {
        const float* qp = qb + (size_t)(mi * 16 + lr) * DH + c * 32 + lg * 8;
        float t[8];
        *(float4*)t       = *(const float4*)qp;
        *(float4*)(t + 4) = *(const float4*)(qp + 4);
        qf[mi][c] = pack8(t);
      }
  }

  f32x4 o[2][8];
#pragma unroll
  for (int mi = 0; mi < 2; ++mi)
#pragma unroll
    for (int nd = 0; nd < 8; ++nd) o[mi][nd] = (f32x4){0.f, 0.f, 0.f, 0.f};
  float mrun[2][4], lrun[2][4];
#pragma unroll
  for (int mi = 0; mi < 2; ++mi)
#pragma unroll
    for (int r = 0; r < 4; ++r) { mrun[mi][r] = -1e30f; lrun[mi][r] = 0.f; }

  const char* kb_base = kf_g + (size_t)(b * NHK + hk) * 262144 + l * 16;
  const char* vb_base = vf_g + (size_t)(b * NHK + hk) * 262144 + l * 16;
  const float* mk_base = mask + (size_t)b * SQ * SK;
  const float SCALE = 0.08838834764831845f;  // 1/sqrt(128)
  const float L2E   = 1.4426950408889634f;
  u16* plw = pl + w * 32 * 88;

  for (int t = 0; t < 16; ++t) {
    const int kb = t * 64;
    // ---- QK^T: S[32q x 64k] per wave, K-frags from global (L2) ----
    f32x4 s[2][4];
#pragma unroll
    for (int mi = 0; mi < 2; ++mi)
#pragma unroll
      for (int ni = 0; ni < 4; ++ni) s[mi][ni] = (f32x4){0.f, 0.f, 0.f, 0.f};
#pragma unroll
    for (int ni = 0; ni < 4; ++ni)
#pragma unroll
      for (int c = 0; c < 4; ++c) {
        bf16x8 kf = *(const bf16x8*)(kb_base + t * 16384 + (ni * 4 + c) * 1024);
        s[0][ni] = mfma16(qf[0][c], kf, s[0][ni]);
        s[1][ni] = mfma16(qf[1][c], kf, s[1][ni]);
      }

    // ---- mask + online softmax (row = lg*4+r within 16; reduce over l&15) --
#pragma unroll
    for (int mi = 0; mi < 2; ++mi) {
      float x[4][4];
#pragma unroll
      for (int ni = 0; ni < 4; ++ni)
#pragma unroll
        for (int r = 0; r < 4; ++r) {
          int grow = q0 + w * 32 + mi * 16 + lg * 4 + r;
          float mv = mk_base[(size_t)grow * SK + kb + ni * 16 + lr];
          x[ni][r] = s[mi][ni][r] * SCALE + mv;
        }
      float tm[4], fac[4];
#pragma unroll
      for (int r = 0; r < 4; ++r) {
        float v = fmaxf(fmaxf(x[0][r], x[1][r]), fmaxf(x[2][r], x[3][r]));
        v = fmaxf(v, __shfl_xor(v, 1));
        v = fmaxf(v, __shfl_xor(v, 2));
        v = fmaxf(v, __shfl_xor(v, 4));
        v = fmaxf(v, __shfl_xor(v, 8));
        float mnew = fmaxf(mrun[mi][r], v);
        fac[r] = exp2f((mrun[mi][r] - mnew) * L2E);
        mrun[mi][r] = mnew;
        tm[r] = mnew;
      }
#pragma unroll
      for (int ni = 0; ni < 4; ++ni)
#pragma unroll
        for (int r = 0; r < 4; ++r) {
          float p = exp2f((x[ni][r] - tm[r]) * L2E);
          x[ni][r] = p;
          plw[(mi * 16 + lg * 4 + r) * 88 + ni * 16 + lr] = f2bf(p);
        }
#pragma unroll
      for (int r = 0; r < 4; ++r) {
        float sum = x[0][r] + x[1][r] + x[2][r] + x[3][r];
        sum += __shfl_xor(sum, 1);
        sum += __shfl_xor(sum, 2);
        sum += __shfl_xor(sum, 4);
        sum += __shfl_xor(sum, 8);
        lrun[mi][r] = lrun[mi][r] * fac[r] + sum;
      }
#pragma unroll
      for (int nd = 0; nd < 8; ++nd)
#pragma unroll
        for (int r = 0; r < 4; ++r) o[mi][nd][r] *= fac[r];
    }

    // ---- PV: O += P[32x64] * V[64x128], V-frags from global (L2) ----
#pragma unroll
    for (int ks = 0; ks < 2; ++ks) {
      bf16x8 pf0 = *(const bf16x8*)((const char*)plw + (0 * 16 + lr) * 176 + ks * 64 + lg * 16);
      bf16x8 pf1 = *(const bf16x8*)((const char*)plw + (1 * 16 + lr) * 176 + ks * 64 + lg * 16);
#pragma unroll
      for (int nd = 0; nd < 8; ++nd) {
        bf16x8 vf = *(const bf16x8*)(vb_base + t * 16384 + (ks * 8 + nd) * 1024);
        o[0][nd] = mfma16(pf0, vf, o[0][nd]);
        o[1][nd] = mfma16(pf1, vf, o[1][nd]);
      }
    }
  }

  // ---- epilogue: normalize, write bf16 A row [b*1024+q][h*128+d] ----
#pragma unroll
  for (int mi = 0; mi < 2; ++mi)
#pragma unroll
    for (int nd = 0; nd < 8; ++nd)
#pragma unroll
      for (int r = 0; r < 4; ++r) {
        int grow = q0 + w * 32 + mi * 16 + lg * 4 + r;
        size_t m = (size_t)b * SQ + grow;
        int col = h * DH + nd * 16 + lr;
        abf[m * HID + col] = f2bf(o[mi][nd][r] / lrun[mi][r]);
      }
}

// ---------------------------------------------------------------------------
// Kernel 5: C[2048][8192] fp32 = A[2048][8192] bf16 · Wt[8192][8192]^T bf16
// 128x128 tile, BK=64, 4 waves (2x2), XCD-swizzled grid, XOR-swizzled LDS
// (linear gload_lds dest + per-lane XOR'd global source + XOR'd ds_read).
// ---------------------------------------------------------------------------
__global__ __launch_bounds__(256) void k_gemm(const u16* __restrict__ A,
                                              const u16* __restrict__ Bt,
                                              float* __restrict__ C) {
  __shared__ char As[16384];
  __shared__ char Bs[16384];
  // bijective XCD swizzle: grid=1024, 8 XCDs, 128 blocks each
  const int bid = blockIdx.x;
  const int logical = (bid & 7) * 128 + (bid >> 3);
  const int m0 = (logical & 15) * 128;   // M fast within an XCD's chunk
  const int n0 = (logical >> 4) * 128;
  const int tid = threadIdx.x;
  const int w = tid >> 6, l = tid & 63;
  const int lr = l & 15, lg = l >> 4;
  const int wr = w >> 1, wc = w & 1;

  f32x4 acc[4][4];
#pragma unroll
  for (int mi = 0; mi < 4; ++mi)
#pragma unroll
    for (int ni = 0; ni < 4; ++ni) acc[mi][ni] = (f32x4){0.f, 0.f, 0.f, 0.f};

  const char* Ab = (const char*)A;
  const char* Bb = (const char*)Bt;

  for (int kt = 0; kt < 8192; kt += 64) {
    // stage 128x64 bf16 tiles, XOR-swizzle via the SOURCE address (rule #21)
#pragma unroll
    for (int j = 0; j < 4; ++j) {
      int is = w * 4 + j;            // wave-uniform 0..15
      int ch = is * 64 + l;          // 0..1023
      int row = ch >> 3, cg = ch & 7;
      int cgs = cg ^ (row & 7);
      gload_lds16(Ab + ((size_t)(m0 + row) * 8192 + kt + cgs * 8) * 2, As + is * 1024);
      gload_lds16(Bb + ((size_t)(n0 + row) * 8192 + kt + cgs * 8) * 2, Bs + is * 1024);
    }
    __syncthreads();
    bf16x8 af[4][2], bfr[4][2];
#pragma unroll
    for (int i = 0; i < 4; ++i) {
      int ra = wr * 64 + i * 16 + lr;
      int rb = wc * 64 + i * 16 + lr;
#pragma unroll
      for (int cc = 0; cc < 2; ++cc) {
        af[i][cc]  = *(const bf16x8*)(As + ra * 128 + ((cc * 64 + lg * 16) ^ ((ra & 7) << 4)));
        bfr[i][cc] = *(const bf16x8*)(Bs + rb * 128 + ((cc * 64 + lg * 16) ^ ((rb & 7) << 4)));
      }
    }
#pragma unroll
    for (int mi = 0; mi < 4; ++mi)
#pragma unroll
      for (int ni = 0; ni < 4; ++ni) {
        acc[mi][ni] = mfma16(af[mi][0], bfr[ni][0], acc[mi][ni]);
        acc[mi][ni] = mfma16(af[mi][1], bfr[ni][1], acc[mi][ni]);
      }
    __syncthreads();
  }

#pragma unroll
  for (int mi = 0; mi < 4; ++mi)
#pragma unroll
    for (int ni = 0; ni < 4; ++ni)
#pragma unroll
      for (int r = 0; r < 4; ++r)
        C[(size_t)(m0 + wr * 64 + mi * 16 + lg * 4 + r) * 8192 +
          n0 + wc * 64 + ni * 16 + lr] = acc[mi][ni][r];
}

// ---------------------------------------------------------------------------
extern "C" void kernel_launch(void* const* d_in, const int* in_sizes, int n_in,
                              void* d_out, int out_size, void* d_ws, size_t ws_size,
                              hipStream_t stream) {
  const float* xq     = (const float*)d_in[0];
  const float* keys   = (const float*)d_in[1];
  const float* values = (const float*)d_in[2];
  const float* mask   = (const float*)d_in[3];
  const float* wo     = (const float*)d_in[4];
  float* out = (float*)d_out;

  // ws layout (~168 MB):
  //   [0, 32M)          A bf16 (attn out, [2048][8192])
  //   [32M, 160M)       Wt bf16 (wo^T, [8192][8192])
  //   [+4M][+4M]        Kf / Vf bf16 fragment-major
  char* ws = (char*)d_ws;
  u16*  Abf = (u16*)ws;
  u16*  Wt  = (u16*)(ws + 33554432ull);
  char* Kf  = ws + 33554432ull + 134217728ull;
  char* Vf  = Kf + 4194304ull;

  hipLaunchKernelGGL(k_wo_t,  dim3(16384), dim3(256), 0, stream, wo, Wt);
  hipLaunchKernelGGL(k_cvt_k, dim3(1024),  dim3(256), 0, stream, keys, Kf);
  hipLaunchKernelGGL(k_cvt_v, dim3(1024),  dim3(256), 0, stream, values, Vf);
  hipLaunchKernelGGL(k_attn,  dim3(8, 64, 2), dim3(256), 0, stream,
                     xq, Kf, Vf, mask, Abf);
  hipLaunchKernelGGL(k_gemm,  dim3(1024),  dim3(256), 0, stream, Abf, Wt, out);
}

// Round 3
// 532.856 us; speedup vs baseline: 1.8545x; 1.5898x over previous
//
#include <hip/hip_runtime.h>
#include <hip/hip_bf16.h>
#include <stdint.h>

// Problem constants
#define NB   2
#define NH   64
#define NHK  8
#define SQ   1024
#define SK   1024
#define DH   128
#define HID  8192     // NH*DH
#define MROWS 2048    // NB*SQ
#define NT   128      // GEMM K-tiles: 8192/64

typedef unsigned short u16;
typedef __bf16 bf16_t;
typedef bf16_t bf16x8 __attribute__((ext_vector_type(8)));
typedef float  f32x4  __attribute__((ext_vector_type(4)));
typedef u16    u16x8  __attribute__((ext_vector_type(8)));
typedef u16    u16x4  __attribute__((ext_vector_type(4)));

#define DEV __device__ __forceinline__

DEV u16 f2bf(float f) {
  uint32_t u = __builtin_bit_cast(uint32_t, f);
  u += 0x7fffu + ((u >> 16) & 1u);   // RNE
  return (u16)(u >> 16);
}

DEV bf16x8 pack8(const float* v) {
  u16x8 r;
#pragma unroll
  for (int i = 0; i < 8; ++i) r[i] = f2bf(v[i]);
  return __builtin_bit_cast(bf16x8, r);
}

DEV f32x4 mfma16(bf16x8 a, bf16x8 b, f32x4 c) {
  return __builtin_amdgcn_mfma_f32_16x16x32_bf16(a, b, c, 0, 0, 0);
}

// async global->LDS, 16B per lane; lds dest must be wave-uniform base
DEV void gload_lds16(const void* g, void* l) {
  __builtin_amdgcn_global_load_lds(
      (const __attribute__((address_space(1))) void*)g,
      (__attribute__((address_space(3))) void*)l, 16, 0, 0);
}

#define BAR()  asm volatile("s_barrier" ::: "memory")
#define VMC(n) asm volatile("s_waitcnt vmcnt(" #n ")" ::: "memory")

// ---------------------------------------------------------------------------
// Kernel 1: wo [K=8192][N=8192] fp32 -> Wt [N][K] bf16 (transpose + convert)
// ---------------------------------------------------------------------------
__global__ __launch_bounds__(256) void k_wo_t(const float* __restrict__ wo,
                                              u16* __restrict__ wt) {
  __shared__ u16 tile[64][72];  // [k-local][n-local], padded
  const int t  = threadIdx.x;
  const int k0 = (blockIdx.x & 127) * 64;
  const int n0 = (blockIdx.x >> 7) * 64;
  const int r  = t >> 4, cg = t & 15;
#pragma unroll
  for (int p = 0; p < 4; ++p) {
    int row = r + p * 16;  // k-local
    float4 v = *(const float4*)(wo + (size_t)(k0 + row) * 8192 + n0 + cg * 4);
    tile[row][cg * 4 + 0] = f2bf(v.x);
    tile[row][cg * 4 + 1] = f2bf(v.y);
    tile[row][cg * 4 + 2] = f2bf(v.z);
    tile[row][cg * 4 + 3] = f2bf(v.w);
  }
  __syncthreads();
#pragma unroll
  for (int p = 0; p < 4; ++p) {
    int row = r + p * 16;  // n-local
    u16x4 ov;
    ov[0] = tile[cg * 4 + 0][row];
    ov[1] = tile[cg * 4 + 1][row];
    ov[2] = tile[cg * 4 + 2][row];
    ov[3] = tile[cg * 4 + 3][row];
    *(u16x4*)(wt + (size_t)(n0 + row) * 8192 + k0 + cg * 4) = ov;
  }
}

// ---------------------------------------------------------------------------
// Kernel 2: keys fp32 [head][kpos][d] -> Kf bf16 FRAGMENT-MAJOR (B-operand
// 1KB blocks; lane l: K[t*64+ni*16+(l&15)][c*32+(l>>4)*8+j])
// ---------------------------------------------------------------------------
__global__ __launch_bounds__(256) void k_cvt_k(const float* __restrict__ keys,
                                               char* __restrict__ kf) {
  int g = blockIdx.x * 256 + threadIdx.x;  // 262144 chunks of 16B
  int l    = g & 63;
  int blk  = (g >> 6) & 15;
  int t    = (g >> 10) & 15;
  int head = g >> 14;
  int ni = blk >> 2, c = blk & 3;
  int row = t * 64 + ni * 16 + (l & 15);
  int col = c * 32 + (l >> 4) * 8;
  const float* src = keys + ((size_t)head * 1024 + row) * 128 + col;
  float tb[8];
  *(float4*)tb       = *(const float4*)src;
  *(float4*)(tb + 4) = *(const float4*)(src + 4);
  u16x8 r;
#pragma unroll
  for (int i = 0; i < 8; ++i) r[i] = f2bf(tb[i]);
  *(u16x8*)(kf + (size_t)g * 16) = r;
}

// ---------------------------------------------------------------------------
// Kernel 3: values fp32 [head][kpos][d] -> Vf bf16 FRAGMENT-MAJOR (B-operand:
// lane l: V[t*64+ks*32+(l>>4)*8+j][nd*16+(l&15)])
// ---------------------------------------------------------------------------
__global__ __launch_bounds__(256) void k_cvt_v(const float* __restrict__ values,
                                               char* __restrict__ vf) {
  int g = blockIdx.x * 256 + threadIdx.x;
  int l    = g & 63;
  int blk  = (g >> 6) & 15;
  int t    = (g >> 10) & 15;
  int head = g >> 14;
  int ks = blk >> 3, nd = blk & 7;
  int k0 = t * 64 + ks * 32 + (l >> 4) * 8;
  int d  = nd * 16 + (l & 15);
  const float* src = values + (size_t)head * 131072 + (size_t)k0 * 128 + d;
  u16x8 r;
#pragma unroll
  for (int j = 0; j < 8; ++j) r[j] = f2bf(src[j * 128]);
  *(u16x8*)(vf + (size_t)g * 16) = r;
}

// ---------------------------------------------------------------------------
// Kernel 4: flash attention, zero-barrier main loop (unchanged from R2 except
// setprio around MFMA clusters).
// ---------------------------------------------------------------------------
__global__ __launch_bounds__(256) void k_attn(
    const float* __restrict__ xq, const char* __restrict__ kf_g,
    const char* __restrict__ vf_g, const float* __restrict__ mask,
    u16* __restrict__ abf) {
  __shared__ u16 pl[4 * 32 * 88];   // per-wave P [32][88-padded]

  const int b = blockIdx.z, h = blockIdx.y;
  const int q0 = blockIdx.x * 128;
  const int hk = h >> 3;
  const int tid = threadIdx.x;
  const int w = tid >> 6, l = tid & 63;
  const int lr = l & 15, lg = l >> 4;

  bf16x8 qf[2][4];
  {
    const float* qb = xq + (((size_t)(b * NH + h) * SQ) + q0 + w * 32) * DH;
#pragma unroll
    for (int mi = 0; mi < 2; ++mi)
#pragma unroll
      for (int c = 0; c < 4; ++c) {
        const float* qp = qb + (size_t)(mi * 16 + lr) * DH + c * 32 + lg * 8;
        float t[8];
        *(float4*)t       = *(const float4*)qp;
        *(float4*)(t + 4) = *(const float4*)(qp + 4);
        qf[mi][c] = pack8(t);
      }
  }

  f32x4 o[2][8];
#pragma unroll
  for (int mi = 0; mi < 2; ++mi)
#pragma unroll
    for (int nd = 0; nd < 8; ++nd) o[mi][nd] = (f32x4){0.f, 0.f, 0.f, 0.f};
  float mrun[2][4], lrun[2][4];
#pragma unroll
  for (int mi = 0; mi < 2; ++mi)
#pragma unroll
    for (int r = 0; r < 4; ++r) { mrun[mi][r] = -1e30f; lrun[mi][r] = 0.f; }

  const char* kb_base = kf_g + (size_t)(b * NHK + hk) * 262144 + l * 16;
  const char* vb_base = vf_g + (size_t)(b * NHK + hk) * 262144 + l * 16;
  const float* mk_base = mask + (size_t)b * SQ * SK;
  const float SCALE = 0.08838834764831845f;  // 1/sqrt(128)
  const float L2E   = 1.4426950408889634f;
  u16* plw = pl + w * 32 * 88;

  for (int t = 0; t < 16; ++t) {
    const int kb = t * 64;
    f32x4 s[2][4];
#pragma unroll
    for (int mi = 0; mi < 2; ++mi)
#pragma unroll
      for (int ni = 0; ni < 4; ++ni) s[mi][ni] = (f32x4){0.f, 0.f, 0.f, 0.f};
    __builtin_amdgcn_s_setprio(1);
#pragma unroll
    for (int ni = 0; ni < 4; ++ni)
#pragma unroll
      for (int c = 0; c < 4; ++c) {
        bf16x8 kf = *(const bf16x8*)(kb_base + t * 16384 + (ni * 4 + c) * 1024);
        s[0][ni] = mfma16(qf[0][c], kf, s[0][ni]);
        s[1][ni] = mfma16(qf[1][c], kf, s[1][ni]);
      }
    __builtin_amdgcn_s_setprio(0);

#pragma unroll
    for (int mi = 0; mi < 2; ++mi) {
      float x[4][4];
#pragma unroll
      for (int ni = 0; ni < 4; ++ni)
#pragma unroll
        for (int r = 0; r < 4; ++r) {
          int grow = q0 + w * 32 + mi * 16 + lg * 4 + r;
          float mv = mk_base[(size_t)grow * SK + kb + ni * 16 + lr];
          x[ni][r] = s[mi][ni][r] * SCALE + mv;
        }
      float tm[4], fac[4];
#pragma unroll
      for (int r = 0; r < 4; ++r) {
        float v = fmaxf(fmaxf(x[0][r], x[1][r]), fmaxf(x[2][r], x[3][r]));
        v = fmaxf(v, __shfl_xor(v, 1));
        v = fmaxf(v, __shfl_xor(v, 2));
        v = fmaxf(v, __shfl_xor(v, 4));
        v = fmaxf(v, __shfl_xor(v, 8));
        float mnew = fmaxf(mrun[mi][r], v);
        fac[r] = exp2f((mrun[mi][r] - mnew) * L2E);
        mrun[mi][r] = mnew;
        tm[r] = mnew;
      }
#pragma unroll
      for (int ni = 0; ni < 4; ++ni)
#pragma unroll
        for (int r = 0; r < 4; ++r) {
          float p = exp2f((x[ni][r] - tm[r]) * L2E);
          x[ni][r] = p;
          plw[(mi * 16 + lg * 4 + r) * 88 + ni * 16 + lr] = f2bf(p);
        }
#pragma unroll
      for (int r = 0; r < 4; ++r) {
        float sum = x[0][r] + x[1][r] + x[2][r] + x[3][r];
        sum += __shfl_xor(sum, 1);
        sum += __shfl_xor(sum, 2);
        sum += __shfl_xor(sum, 4);
        sum += __shfl_xor(sum, 8);
        lrun[mi][r] = lrun[mi][r] * fac[r] + sum;
      }
#pragma unroll
      for (int nd = 0; nd < 8; ++nd)
#pragma unroll
        for (int r = 0; r < 4; ++r) o[mi][nd][r] *= fac[r];
    }

    __builtin_amdgcn_s_setprio(1);
#pragma unroll
    for (int ks = 0; ks < 2; ++ks) {
      bf16x8 pf0 = *(const bf16x8*)((const char*)plw + (0 * 16 + lr) * 176 + ks * 64 + lg * 16);
      bf16x8 pf1 = *(const bf16x8*)((const char*)plw + (1 * 16 + lr) * 176 + ks * 64 + lg * 16);
#pragma unroll
      for (int nd = 0; nd < 8; ++nd) {
        bf16x8 vf = *(const bf16x8*)(vb_base + t * 16384 + (ks * 8 + nd) * 1024);
        o[0][nd] = mfma16(pf0, vf, o[0][nd]);
        o[1][nd] = mfma16(pf1, vf, o[1][nd]);
      }
    }
    __builtin_amdgcn_s_setprio(0);
  }

#pragma unroll
  for (int mi = 0; mi < 2; ++mi)
#pragma unroll
    for (int nd = 0; nd < 8; ++nd)
#pragma unroll
      for (int r = 0; r < 4; ++r) {
        int grow = q0 + w * 32 + mi * 16 + lg * 4 + r;
        size_t m = (size_t)b * SQ + grow;
        int col = h * DH + nd * 16 + lr;
        abf[m * HID + col] = f2bf(o[mi][nd][r] / lrun[mi][r]);
      }
}

// ---------------------------------------------------------------------------
// Kernel 5: C[2048][8192] = A[2048][8192]bf16 · Wt[8192][8192]^T bf16
// 256x256 tile, BK=64, 8 waves (2Mx4N, stripe-interleaved quadrants),
// 8-phase (4 phases/tile, 2 barriers/phase), counted vmcnt(6), T2 swizzle,
// setprio, XCD-swizzled grid. LDS 128KB = 2 tiles x 4 x 16KB halves.
// Half-tile free/stage schedule (per iter t, c=t&1):
//   LDS reads: p0: A-s0+B-s0, p1: B-s1, p2: A-s1, p3: none (reg reuse)
//   stages:    p0: A-s1(t+1)->c^1, p1: A-s0(t+2)->c, p2: B-s0(t+2)->c,
//              p3: B-s1(t+2)->c ; vmcnt(6) at p3 => tile t+1 fully landed,
//              3 half-tiles stay in flight across the barrier.
// ---------------------------------------------------------------------------
__global__ __launch_bounds__(512, 2) void k_gemm(const u16* __restrict__ A,
                                                 const u16* __restrict__ Bt,
                                                 float* __restrict__ C) {
  __shared__ char L[131072];
  // grid 256 = 8m x 32n; XCD swizzle: each XCD gets all 8 m x 4 n strips
  const int bid = blockIdx.x;
  const int logical = (bid & 7) * 32 + (bid >> 3);
  const int m0 = (logical & 7) * 256;
  const int n0 = (logical >> 3) * 256;
  const int tid = threadIdx.x;
  const int w = tid >> 6, l = tid & 63;
  const int lr = l & 15, lg = l >> 4;
  const int wm = w >> 2, wn = w & 3;   // 2M x 4N

  // staging coords: chunk ch=j*512+tid -> row=ch>>3, col-chunk=(ch&7)^(row&7)
  int srow[2], scol[2];
#pragma unroll
  for (int j = 0; j < 2; ++j) {
    int ch = j * 512 + tid;
    srow[j] = ch >> 3;
    scol[j] = (ch & 7) ^ (srow[j] & 7);
  }

  const char* Ab = (const char*)A;
  const char* Bb = (const char*)Bt;

#define STAGE(gb, row0, tt, dst) do {                                          \
    int kt_ = ((tt) < NT ? (tt) : 0) * 64;                                     \
    _Pragma("unroll")                                                          \
    for (int j_ = 0; j_ < 2; ++j_)                                             \
      gload_lds16((gb) + ((size_t)((row0) + srow[j_]) * 8192 + kt_ +           \
                          scol[j_] * 8) * 2,                                   \
                  (dst) + j_ * 8192 + (w << 10));                              \
  } while (0)

#define LDA(base, hs) do {                                                     \
    _Pragma("unroll")                                                          \
    for (int mi_ = 0; mi_ < 4; ++mi_) {                                        \
      int r_ = wm * 64 + mi_ * 16 + lr;                                        \
      _Pragma("unroll")                                                        \
      for (int ks_ = 0; ks_ < 2; ++ks_)                                        \
        bA[mi_][ks_] = *(const bf16x8*)(L + (base) + (hs) * 16384 + r_ * 128 + \
                        ((ks_ * 64 + lg * 16) ^ ((r_ & 7) << 4)));             \
    }                                                                          \
  } while (0)

#define LDB(dst, base, hs) do {                                                \
    _Pragma("unroll")                                                          \
    for (int ni_ = 0; ni_ < 2; ++ni_) {                                        \
      int r_ = wn * 32 + ni_ * 16 + lr;                                        \
      _Pragma("unroll")                                                        \
      for (int ks_ = 0; ks_ < 2; ++ks_)                                        \
        dst[ni_][ks_] = *(const bf16x8*)(L + (base) + 32768 + (hs) * 16384 +   \
                        r_ * 128 + ((ks_ * 64 + lg * 16) ^ ((r_ & 7) << 4)));  \
    }                                                                          \
  } while (0)

#define MM(mh, nh, BB) do {                                                    \
    __builtin_amdgcn_s_setprio(1);                                             \
    _Pragma("unroll")                                                          \
    for (int mi_ = 0; mi_ < 4; ++mi_)                                          \
      _Pragma("unroll")                                                        \
      for (int ni_ = 0; ni_ < 2; ++ni_)                                        \
        _Pragma("unroll")                                                      \
        for (int ks_ = 0; ks_ < 2; ++ks_)                                      \
          acc[mh][nh][mi_][ni_] =                                              \
              mfma16(bA[mi_][ks_], BB[ni_][ks_], acc[mh][nh][mi_][ni_]);       \
    __builtin_amdgcn_s_setprio(0);                                             \
  } while (0)

  f32x4 acc[2][2][4][2];
#pragma unroll
  for (int a1 = 0; a1 < 2; ++a1)
#pragma unroll
    for (int a2 = 0; a2 < 2; ++a2)
#pragma unroll
      for (int a3 = 0; a3 < 4; ++a3)
#pragma unroll
        for (int a4 = 0; a4 < 2; ++a4)
          acc[a1][a2][a3][a4] = (f32x4){0.f, 0.f, 0.f, 0.f};

  bf16x8 bA[4][2], bB0[2][2], bB1[2][2];

  // prologue: tile0 (all 4 halves) + tile1 (A-s0,B-s0,B-s1)
  STAGE(Ab, m0,       0, L + 0);
  STAGE(Bb, n0,       0, L + 32768);
  STAGE(Bb, n0 + 128, 0, L + 49152);
  STAGE(Ab, m0 + 128, 0, L + 16384);
  STAGE(Ab, m0,       1, L + 65536);
  STAGE(Bb, n0,       1, L + 65536 + 32768);
  STAGE(Bb, n0 + 128, 1, L + 65536 + 49152);
  VMC(6);   // oldest 4 halves (tile 0) landed
  BAR();

  for (int t = 0; t < NT; ++t) {
    const int c  = (t & 1) << 16;
    const int cn = c ^ 65536;
    // ---- phase 0: quadrant (0,0) ----
    STAGE(Ab, m0 + 128, t + 1, L + cn + 16384);   // A-s1(t+1)
    LDA(c, 0);
    LDB(bB0, c, 0);
    BAR();
    MM(0, 0, bB0);
    BAR();
    // ---- phase 1: quadrant (0,1) ----
    STAGE(Ab, m0, t + 2, L + c + 0);              // A-s0(t+2)
    LDB(bB1, c, 1);
    BAR();
    MM(0, 1, bB1);
    BAR();
    // ---- phase 2: quadrant (1,1) ----
    STAGE(Bb, n0, t + 2, L + c + 32768);          // B-s0(t+2)
    LDA(c, 1);
    BAR();
    MM(1, 1, bB1);
    BAR();
    // ---- phase 3: quadrant (1,0) ----
    STAGE(Bb, n0 + 128, t + 2, L + c + 49152);    // B-s1(t+2)
    BAR();
    MM(1, 0, bB0);
    VMC(6);   // tile t+1 fully landed; 3 halves stay in flight
    BAR();
  }
  VMC(0);   // drain DMA before LDS dealloc / epilogue

  // epilogue: C rows m0 + mh*128 + wm*64 + mi*16 + lg*4+rr,
  //           cols n0 + nh*128 + wn*32 + ni*16 + lr
#pragma unroll
  for (int mh = 0; mh < 2; ++mh)
#pragma unroll
    for (int nh = 0; nh < 2; ++nh)
#pragma unroll
      for (int mi = 0; mi < 4; ++mi)
#pragma unroll
        for (int ni = 0; ni < 2; ++ni)
#pragma unroll
          for (int rr = 0; rr < 4; ++rr)
            C[(size_t)(m0 + mh * 128 + wm * 64 + mi * 16 + lg * 4 + rr) * 8192 +
              n0 + nh * 128 + wn * 32 + ni * 16 + lr] = acc[mh][nh][mi][ni][rr];
#undef STAGE
#undef LDA
#undef LDB
#undef MM
}

// ---------------------------------------------------------------------------
extern "C" void kernel_launch(void* const* d_in, const int* in_sizes, int n_in,
                              void* d_out, int out_size, void* d_ws, size_t ws_size,
                              hipStream_t stream) {
  const float* xq     = (const float*)d_in[0];
  const float* keys   = (const float*)d_in[1];
  const float* values = (const float*)d_in[2];
  const float* mask   = (const float*)d_in[3];
  const float* wo     = (const float*)d_in[4];
  float* out = (float*)d_out;

  char* ws = (char*)d_ws;
  u16*  Abf = (u16*)ws;
  u16*  Wt  = (u16*)(ws + 33554432ull);
  char* Kf  = ws + 33554432ull + 134217728ull;
  char* Vf  = Kf + 4194304ull;

  hipLaunchKernelGGL(k_wo_t,  dim3(16384), dim3(256), 0, stream, wo, Wt);
  hipLaunchKernelGGL(k_cvt_k, dim3(1024),  dim3(256), 0, stream, keys, Kf);
  hipLaunchKernelGGL(k_cvt_v, dim3(1024),  dim3(256), 0, stream, values, Vf);
  hipLaunchKernelGGL(k_attn,  dim3(8, 64, 2), dim3(256), 0, stream,
                     xq, Kf, Vf, mask, Abf);
  hipLaunchKernelGGL(k_gemm,  dim3(256),   dim3(512), 0, stream, Abf, Wt, out);
}